// Round 17
// baseline (271.340 us; speedup 1.0000x reference)
//
#include <hip/hip_runtime.h>
#include <hip/hip_bf16.h>
#include <hip/hip_cooperative_groups.h>
#include <stdint.h>

namespace cg = cooperative_groups;

typedef __attribute__((ext_vector_type(8))) __bf16 bf16x8;
typedef __attribute__((ext_vector_type(4))) float f32x4;
typedef __attribute__((ext_vector_type(4))) uint u32x4;

#define C192 192
#define NSP 65536
#define EPS_N 1e-12f

// per-slice compact partial layout (bf16): 78 full 16x16 tiles (lane-major) + 12 ones-col tiles(16)
#define SLICE_ELEMS 20224
#define ONES_OFF_E 19968   // 78*256

__device__ __forceinline__ uint32_t f2bf1(float a){
  uint32_t u = __float_as_uint(a);
  return (u + 0x7fffu + ((u >> 16) & 1u)) >> 16;
}
__device__ __forceinline__ uint32_t f2bf2(float lo, float hi){
  return f2bf1(lo) | (f2bf1(hi) << 16);
}
__device__ __forceinline__ float bf2f(ushort u){
  return __uint_as_float(((uint32_t)u) << 16);
}

// ---------------- K1: Gram upper-tri partials via global_load_lds (R16-identical)
// grid 256: b = bid>>7, slice = bid&127 handles x[b][:, slice*512 .. +512), 16 chunks x 32 cols.
__global__ __launch_bounds__(768, 4) void k_gram(const float* __restrict__ x,
                                                 ushort* __restrict__ gpart){
  __shared__ float xs[2 * 6144];   // 2 x 24576 B
  char* lb = (char*)xs;
  const int tid = threadIdx.x;
  const int lane = tid & 63, wid = tid >> 6;      // 12 waves
  const int l15 = lane & 15, hi = lane >> 4;
  const int b = blockIdx.x >> 7, slice = blockIdx.x & 127;
  const int j0 = slice * 512;

  const int p = (wid < 6) ? wid : (wid - 6);
  const int nFirst = 5 - p;                        // for wid>=6: tiles 0..nFirst-1 are row p
  const float* xg = x + ((size_t)b * C192) * NSP + j0;

  const int swcol = ((lane & 7) ^ (lane >> 3)) * 4;
  const float* srow = xg + (size_t)(wid * 16 + (lane >> 3)) * NSP + swcol;

  auto ISSUE = [&](int c, int bi){
    char* dst = lb + bi * 24576 + wid * 2048;      // wave-uniform base; HW adds lane*16
    const float* s0 = srow + c * 32;
    const float* s1 = s0 + (size_t)8 * NSP;
    __builtin_amdgcn_global_load_lds((__attribute__((address_space(1))) const void*)s0,
                                     (__attribute__((address_space(3))) void*)(dst), 16, 0, 0);
    __builtin_amdgcn_global_load_lds((__attribute__((address_space(1))) const void*)s1,
                                     (__attribute__((address_space(3))) void*)(dst + 1024), 16, 0, 0);
  };

  f32x4 acc[8];
  #pragma unroll
  for (int t = 0; t < 8; t++) acc[t] = (f32x4){0.f, 0.f, 0.f, 0.f};

  uint ov = (l15 == 0) ? 0x3F803F80u : 0u;
  u32x4 oq = {ov, ov, ov, ov};
  bf16x8 onesf = __builtin_bit_cast(bf16x8, oq);

  auto LOADFRAG = [&](const char* base, int row) -> bf16x8 {
    int sw = (row & 7) << 4;
    f32x4 v0 = *(const f32x4*)(base + row * 128 + ((hi * 32) ^ sw));
    f32x4 v1 = *(const f32x4*)(base + row * 128 + ((hi * 32 + 16) ^ sw));
    uint w0, w1, w2, w3;
    asm("v_cvt_pk_bf16_f32 %0, %1, %2" : "=v"(w0) : "v"(v0.x), "v"(v0.y));
    asm("v_cvt_pk_bf16_f32 %0, %1, %2" : "=v"(w1) : "v"(v0.z), "v"(v0.w));
    asm("v_cvt_pk_bf16_f32 %0, %1, %2" : "=v"(w2) : "v"(v1.x), "v"(v1.y));
    asm("v_cvt_pk_bf16_f32 %0, %1, %2" : "=v"(w3) : "v"(v1.z), "v"(v1.w));
    u32x4 q = {w0, w1, w2, w3};
    return __builtin_bit_cast(bf16x8, q);
  };

  auto COMPUTE = [&](int bi){
    const char* base = lb + bi * 24576;
    bf16x8 a0 = LOADFRAG(base, p * 16 + l15);
    bf16x8 a1 = (wid >= 6) ? LOADFRAG(base, (11 - p) * 16 + l15) : a0;
    #pragma unroll
    for (int t = 0; t < 8; t++){
      if (wid >= 6 && t >= 7) break;
      int j = (wid < 6) ? (p + t) : ((t < nFirst) ? (p + 8 + t) : (t + 6));
      bf16x8 bf = (j < 12) ? LOADFRAG(base, j * 16 + l15) : onesf;
      bf16x8 aS = (wid < 6 || t < nFirst) ? a0 : a1;
      acc[t] = __builtin_amdgcn_mfma_f32_16x16x32_bf16(aS, bf, acc[t], 0, 0, 0);
    }
  };

  ISSUE(0, 0);
  for (int c = 0; c < 16; c++){
    __syncthreads();                 // implicit vmcnt(0): our chunk-c loads are landed
    if (c < 15) ISSUE(c + 1, (c + 1) & 1);
    COMPUTE(c & 1);
  }

  ushort* gp = gpart + (size_t)(b * 128 + slice) * SLICE_ELEMS;
  #pragma unroll
  for (int t = 0; t < 8; t++){
    if (wid >= 6 && t >= 7) break;
    int i = (wid < 6) ? p : ((t < nFirst) ? p : (11 - p));
    int j = (wid < 6) ? (p + t) : ((t < nFirst) ? (p + 8 + t) : (t + 6));
    uint2 u2;
    u2.x = f2bf2(acc[t][0], acc[t][1]);
    u2.y = f2bf2(acc[t][2], acc[t][3]);
    if (j < 12){
      int F = 12 * i - (i * (i - 1)) / 2 + (j - i);
      *(uint2*)(gp + F * 256 + lane * 4) = u2;
    } else if (l15 == 0){
      *(uint2*)(gp + ONES_OFF_E + i * 16 + hi * 4) = u2;
    }
  }
}

// ---------------- K_MID (cooperative): reduce -> pr/norms -> attn+U -> F/gvec
// grid 384 x 256; phases separated by grid.sync(). Bodies are the R16-verified
// kernels with index re-mapping only.
__global__ __launch_bounds__(256) void k_mid(const ushort* __restrict__ gpart,
                                             float* __restrict__ gaug,
                                             const float* __restrict__ qkv_w,
                                             float* __restrict__ wkT,
                                             const float* __restrict__ qkv_b,
                                             float* __restrict__ pr,
                                             float* __restrict__ norms,
                                             const float* __restrict__ temperature,
                                             float* __restrict__ uaug,
                                             const float* __restrict__ proj_w,
                                             const float* __restrict__ proj_b,
                                             ushort* __restrict__ fb,
                                             float* __restrict__ gvec){
  cg::grid_group grid = cg::this_grid();
  __shared__ float Pc[193];
  __shared__ float red[4];
  __shared__ float bcast;
  __shared__ float uSh;
  __shared__ float pw[192];
  const int blk = blockIdx.x, tid = threadIdx.x;

  // ---- Phase A: reduce compact partials -> G_aug (blocks 0..179); WkT (blocks 180..323)
  if (blk < 180){
    int b = blk / 90, slot = blk % 90;
    int e = tid;
    if (slot < 78){
      float sum = 0.f;
      const ushort* pp = gpart + (size_t)(b * 128) * SLICE_ELEMS + slot * 256 + e;
      #pragma unroll 8
      for (int k2 = 0; k2 < 128; k2++) sum += bf2f(pp[(size_t)k2 * SLICE_ELEMS]);
      int i = 0, off = 0;
      while (slot >= off + (12 - i)){ off += 12 - i; i++; }
      int j = i + (slot - off);
      // lane-major remap: e = lane*4 + r -> row = hi*4+r, col = l15
      int row = ((e >> 6) << 2) | (e & 3);
      int col = (e >> 2) & 15;
      int R = i * 16 + row, Cc = j * 16 + col;
      gaug[((size_t)b * C192 + R) * 193 + Cc] = sum;
      gaug[((size_t)b * C192 + Cc) * 193 + R] = sum;
    } else if (e < 16){
      int i = slot - 78;
      float sum = 0.f;
      const ushort* pp = gpart + (size_t)(b * 128) * SLICE_ELEMS + ONES_OFF_E + i * 16 + e;
      #pragma unroll 8
      for (int k2 = 0; k2 < 128; k2++) sum += bf2f(pp[(size_t)k2 * SLICE_ELEMS]);
      gaug[((size_t)b * C192 + i * 16 + e) * 193 + 192] = sum;
    }
  } else if (blk < 324){
    int idx = (blk - 180) * 256 + tid;   // 36864 total
    int d = idx / 192, e2 = idx % 192;
    wkT[e2 * 192 + d] = qkv_w[(192 + d) * 192 + e2];
  }
  grid.sync();

  // ---- Phase B: P_aug/R_aug rows + norms (2 units per block)
  #pragma unroll
  for (int rep = 0; rep < 2; rep++){
    int unit = blk * 2 + rep;            // 0..767
    int b = unit / 384, which = (unit / 192) % 2, c = unit % 192;
    const float* wrow = qkv_w + (which * 192 + c) * 192;
    float acc = 0.f;
    if (tid < 193){
      const float* g = gaug + (size_t)b * C192 * 193 + tid;
      #pragma unroll 4
      for (int e = 0; e < 192; e++) acc += wrow[e] * g[(size_t)e * 193];
      pr[(((size_t)b * 2 + which) * 192 + c) * 193 + tid] = acc;
    }
    if (tid == 192) uSh = acc;
    float v = (tid < 192) ? acc * wrow[tid] : 0.f;
    for (int o = 32; o > 0; o >>= 1) v += __shfl_down(v, o, 64);
    if ((tid & 63) == 0) red[tid >> 6] = v;
    __syncthreads();
    if (tid == 0){
      float s = red[0] + red[1] + red[2] + red[3];
      float bias = qkv_b[which * 192 + c];
      float n2 = s + 2.f * bias * uSh + 65536.f * bias * bias;
      norms[(b * 2 + which) * 192 + c] = fmaxf(sqrtf(fmaxf(n2, 0.f)), EPS_N);
    }
    __syncthreads();
  }
  grid.sync();

  // ---- Phase C: softmax row -> U_aug row (1 unit per block)
  {
    int b = blk / 192, c = blk % 192;
    if (tid < 193) Pc[tid] = pr[(((size_t)b * 2 + 0) * 192 + c) * 193 + tid];
    __syncthreads();
    int d = tid;
    float logit = -1e30f, pv = 0.f;
    if (d < 192){
      float sS = 0.f;
      #pragma unroll 4
      for (int e = 0; e < 192; e++) sS += Pc[e] * wkT[e * 192 + d];
      float bq = qkv_b[c], bk = qkv_b[192 + d];
      float w2 = pr[(((size_t)b * 2 + 1) * 192 + d) * 193 + 192];
      float Sv = sS + Pc[192] * bk + bq * w2 + 65536.f * bq * bk;
      float nq = norms[(b * 2 + 0) * 192 + c];
      float nk = norms[(b * 2 + 1) * 192 + d];
      logit = temperature[0] * Sv / (nq * nk);
    }
    float m = logit;
    for (int o = 32; o > 0; o >>= 1) m = fmaxf(m, __shfl_down(m, o, 64));
    if ((tid & 63) == 0) red[tid >> 6] = m;
    __syncthreads();
    if (tid == 0) bcast = fmaxf(fmaxf(red[0], red[1]), fmaxf(red[2], red[3]));
    __syncthreads();
    m = bcast;
    pv = (d < 192) ? __expf(logit - m) : 0.f;
    float s = pv;
    for (int o = 32; o > 0; o >>= 1) s += __shfl_down(s, o, 64);
    __syncthreads();
    if ((tid & 63) == 0) red[tid >> 6] = s;
    __syncthreads();
    if (tid == 0) bcast = red[0] + red[1] + red[2] + red[3];
    __syncthreads();
    float aw = (d < 192) ? (pv / bcast) : 0.f;
    __syncthreads();
    if (d < 192) Pc[d] = aw;          // reuse Pc as softmax row
    __syncthreads();
    int e = tid;
    if (e <= 192){
      float acc = 0.f;
      if (e < 192){
        #pragma unroll 4
        for (int d2 = 0; d2 < 192; d2++) acc += Pc[d2] * qkv_w[(384 + d2) * 192 + e];
      } else {
        #pragma unroll 4
        for (int d2 = 0; d2 < 192; d2++) acc += Pc[d2] * qkv_b[384 + d2];
      }
      uaug[((size_t)b * 192 + c) * 193 + e] = acc;
    }
  }
  grid.sync();

  // ---- Phase D: F = proj_w @ U (bf16), g = proj_w@h + proj_b (1 unit per block)
  {
    int b = blk / 192, f = blk % 192;
    if (tid < 192) pw[tid] = proj_w[f * 192 + tid];
    __syncthreads();
    int e = tid;
    if (e <= 192){
      float acc = 0.f;
      const float* u = uaug + (size_t)b * 192 * 193 + e;
      #pragma unroll 4
      for (int c2 = 0; c2 < 192; c2++) acc += pw[c2] * u[(size_t)c2 * 193];
      if (e < 192) fb[((size_t)b * 192 + f) * 192 + e] = (ushort)f2bf1(acc);
      else gvec[b * 192 + f] = acc + proj_b[f];
    }
  }
}

// ---------------- K3: out = F @ x + g 1^T  — operand-swapped MFMA (R16-identical)
__global__ __launch_bounds__(256, 3) void k_out(const float* __restrict__ x,
                                                const ushort* __restrict__ fb,
                                                const float* __restrict__ gvec,
                                                float* __restrict__ out){
  __shared__ ushort xt[128 * 192];   // [sp][chan], row = 384 B
  char* lb = (char*)xt;
  const int tid = threadIdx.x;
  const int lane = tid & 63, wid = tid >> 6;
  const int l15 = lane & 15, hi = lane >> 4;
  const int b = blockIdx.x >> 9, cb = blockIdx.x & 511;
  const int j0 = cb * 128;

  const float* xg = x + ((size_t)b * C192) * NSP + j0;
  #pragma unroll
  for (int half = 0; half < 2; half++){
    float4 ra[12];
    #pragma unroll
    for (int ii = 0; ii < 3; ii++){
      int unit = (half * 3 + ii) * 256 + tid;
      int cp = unit >> 4, s8 = unit & 15;
      int c0 = cp * 2, sp0 = s8 * 8;
      const float* r0 = xg + (size_t)c0 * NSP + sp0;
      const float* r1 = xg + (size_t)(c0 + 1) * NSP + sp0;
      ra[4 * ii]     = *(const float4*)(r0);
      ra[4 * ii + 1] = *(const float4*)(r0 + 4);
      ra[4 * ii + 2] = *(const float4*)(r1);
      ra[4 * ii + 3] = *(const float4*)(r1 + 4);
    }
    #pragma unroll
    for (int ii = 0; ii < 3; ii++){
      int unit = (half * 3 + ii) * 256 + tid;
      int cp = unit >> 4, s8 = unit & 15;
      int c0 = cp * 2, sp0 = s8 * 8;
      float fa[8] = {ra[4*ii].x, ra[4*ii].y, ra[4*ii].z, ra[4*ii].w,
                     ra[4*ii+1].x, ra[4*ii+1].y, ra[4*ii+1].z, ra[4*ii+1].w};
      float fc[8] = {ra[4*ii+2].x, ra[4*ii+2].y, ra[4*ii+2].z, ra[4*ii+2].w,
                     ra[4*ii+3].x, ra[4*ii+3].y, ra[4*ii+3].z, ra[4*ii+3].w};
      #pragma unroll
      for (int s = 0; s < 8; s++){
        int sp = sp0 + s;
        int byte = sp * 384 + c0 * 2;
        byte ^= (((sp & 7) ^ ((sp >> 3) & 7)) << 4);
        uint pk;
        asm("v_cvt_pk_bf16_f32 %0, %1, %2" : "=v"(pk) : "v"(fa[s]), "v"(fc[s]));
        *(uint*)(lb + byte) = pk;
      }
    }
  }

  float gv[3];
  #pragma unroll
  for (int i = 0; i < 3; i++)
    gv[i] = gvec[b * 192 + (wid * 3 + i) * 16 + l15];

  f32x4 acc[3][8];
  #pragma unroll
  for (int i = 0; i < 3; i++)
    #pragma unroll
    for (int j = 0; j < 8; j++)
      acc[i][j] = (f32x4){0.f, 0.f, 0.f, 0.f};

  __syncthreads();

  for (int k = 0; k < 6; k++){
    bf16x8 bF[3];
    #pragma unroll
    for (int i = 0; i < 3; i++){
      const ushort* fr = fb + ((size_t)b * 192 + (wid * 3 + i) * 16 + l15) * 192;
      bF[i] = *(const bf16x8*)(fr + k * 32 + hi * 8);
    }
    #pragma unroll
    for (int ct = 0; ct < 8; ct++){
      int sp = ct * 16 + l15;
      int byte = sp * 384 + k * 64 + hi * 16;
      byte ^= (((sp & 7) ^ ((sp >> 3) & 7)) << 4);
      bf16x8 aX = *(const bf16x8*)(lb + byte);
      #pragma unroll
      for (int i = 0; i < 3; i++)
        acc[i][ct] = __builtin_amdgcn_mfma_f32_16x16x32_bf16(aX, bF[i], acc[i][ct], 0, 0, 0);
    }
  }

  #pragma unroll
  for (int i = 0; i < 3; i++){
    int chan = (wid * 3 + i) * 16 + l15;
    float* ob = out + ((size_t)b * C192 + chan) * NSP + j0;
    #pragma unroll
    for (int ct = 0; ct < 8; ct++){
      float4 v;
      v.x = acc[i][ct][0] + gv[i];
      v.y = acc[i][ct][1] + gv[i];
      v.z = acc[i][ct][2] + gv[i];
      v.w = acc[i][ct][3] + gv[i];
      *(float4*)(ob + ct * 16 + hi * 4) = v;
    }
  }
}

extern "C" void kernel_launch(void* const* d_in, const int* in_sizes, int n_in,
                              void* d_out, int out_size, void* d_ws, size_t ws_size,
                              hipStream_t stream){
  const float* x           = (const float*)d_in[0];
  const float* temperature = (const float*)d_in[1];
  const float* qkv_w       = (const float*)d_in[2];
  const float* qkv_b       = (const float*)d_in[3];
  const float* proj_w      = (const float*)d_in[4];
  const float* proj_b      = (const float*)d_in[5];
  float* out = (float*)d_out;
  char* ws = (char*)d_ws;

  ushort* gpart = (ushort*)(ws);                 // 256*20224*2 = 10,354,688
  float*  gaug  = (float*) (ws + 10354688);      // 296,448
  float*  pr    = (float*) (ws + 10651136);      // 592,896
  float*  wkT   = (float*) (ws + 11244032);      // 147,456
  float*  norms = (float*) (ws + 11391488);      // 3,072
  float*  uaug  = (float*) (ws + 11394560);      // 296,448
  ushort* fb    = (ushort*)(ws + 11691008);      // 147,456
  float*  gvec  = (float*) (ws + 11838464);      // 1,536

  hipLaunchKernelGGL(k_gram, dim3(256), dim3(768), 0, stream, x, gpart);

  void* args[] = {(void*)&gpart, (void*)&gaug, (void*)&qkv_w, (void*)&wkT,
                  (void*)&qkv_b, (void*)&pr, (void*)&norms, (void*)&temperature,
                  (void*)&uaug, (void*)&proj_w, (void*)&proj_b, (void*)&fb,
                  (void*)&gvec};
  hipLaunchCooperativeKernel((void*)k_mid, dim3(384), dim3(256), args, 0, stream);

  hipLaunchKernelGGL(k_out, dim3(1024), dim3(256), 0, stream, x, fb, gvec, out);
}

// Round 18
// 125.740 us; speedup vs baseline: 2.1580x; 2.1580x over previous
//
#include <hip/hip_runtime.h>
#include <hip/hip_bf16.h>
#include <stdint.h>

typedef __attribute__((ext_vector_type(8))) __bf16 bf16x8;
typedef __attribute__((ext_vector_type(4))) float f32x4;
typedef __attribute__((ext_vector_type(4))) uint u32x4;

#define C192 192
#define NSP 65536
#define EPS_N 1e-12f

// per-slice compact partial layout (bf16): 78 full 16x16 tiles (lane-major) + 12 ones-col tiles(16)
#define SLICE_ELEMS 20224
#define ONES_OFF_E 19968   // 78*256

__device__ __forceinline__ uint32_t f2bf1(float a){
  uint32_t u = __float_as_uint(a);
  return (u + 0x7fffu + ((u >> 16) & 1u)) >> 16;
}
__device__ __forceinline__ uint32_t f2bf2(float lo, float hi){
  return f2bf1(lo) | (f2bf1(hi) << 16);
}
__device__ __forceinline__ float bf2f(ushort u){
  return __uint_as_float(((uint32_t)u) << 16);
}

// ---------------- K1: Gram upper-tri partials via global_load_lds (zero staging VGPRs)
// grid 256: b = bid>>7, slice = bid&127 handles x[b][:, slice*512 .. +512), 16 chunks x 32 cols.
// 12 waves; pair p={w, w+6}: wave p -> 8 tiles (i=p, j=p..p+7),
// wave p+6 -> (i=p, j=p+8..12) ++ (i=11-p, j=11-p..12).  acc = 8 tiles max (32 VGPR).
// LDS: 2 x 24KB fp32 chunk [192 rows x 32 cols], rows 128 B, XOR-swizzled 16B granules via
// pre-swizzled SOURCE addresses (linear LDS dest, rule #21).  [R13-verified, best total 125.8]
__global__ __launch_bounds__(768, 4) void k_gram(const float* __restrict__ x,
                                                 ushort* __restrict__ gpart){
  __shared__ float xs[2 * 6144];   // 2 x 24576 B
  char* lb = (char*)xs;
  const int tid = threadIdx.x;
  const int lane = tid & 63, wid = tid >> 6;      // 12 waves
  const int l15 = lane & 15, hi = lane >> 4;
  const int b = blockIdx.x >> 7, slice = blockIdx.x & 127;
  const int j0 = slice * 512;

  const int p = (wid < 6) ? wid : (wid - 6);
  const int nFirst = 5 - p;                        // for wid>=6: tiles 0..nFirst-1 are row p
  const float* xg = x + ((size_t)b * C192) * NSP + j0;

  // per-lane swizzled source column (float index) — same for both q sub-loads
  const int swcol = ((lane & 7) ^ (lane >> 3)) * 4;
  const float* srow = xg + (size_t)(wid * 16 + (lane >> 3)) * NSP + swcol;

  auto ISSUE = [&](int c, int bi){
    char* dst = lb + bi * 24576 + wid * 2048;      // wave-uniform base; HW adds lane*16
    const float* s0 = srow + c * 32;
    const float* s1 = s0 + (size_t)8 * NSP;
    __builtin_amdgcn_global_load_lds((__attribute__((address_space(1))) const void*)s0,
                                     (__attribute__((address_space(3))) void*)(dst), 16, 0, 0);
    __builtin_amdgcn_global_load_lds((__attribute__((address_space(1))) const void*)s1,
                                     (__attribute__((address_space(3))) void*)(dst + 1024), 16, 0, 0);
  };

  f32x4 acc[8];
  #pragma unroll
  for (int t = 0; t < 8; t++) acc[t] = (f32x4){0.f, 0.f, 0.f, 0.f};

  uint ov = (l15 == 0) ? 0x3F803F80u : 0u;
  u32x4 oq = {ov, ov, ov, ov};
  bf16x8 onesf = __builtin_bit_cast(bf16x8, oq);

  auto LOADFRAG = [&](const char* base, int row) -> bf16x8 {
    int sw = (row & 7) << 4;
    f32x4 v0 = *(const f32x4*)(base + row * 128 + ((hi * 32) ^ sw));
    f32x4 v1 = *(const f32x4*)(base + row * 128 + ((hi * 32 + 16) ^ sw));
    uint w0, w1, w2, w3;
    asm("v_cvt_pk_bf16_f32 %0, %1, %2" : "=v"(w0) : "v"(v0.x), "v"(v0.y));
    asm("v_cvt_pk_bf16_f32 %0, %1, %2" : "=v"(w1) : "v"(v0.z), "v"(v0.w));
    asm("v_cvt_pk_bf16_f32 %0, %1, %2" : "=v"(w2) : "v"(v1.x), "v"(v1.y));
    asm("v_cvt_pk_bf16_f32 %0, %1, %2" : "=v"(w3) : "v"(v1.z), "v"(v1.w));
    u32x4 q = {w0, w1, w2, w3};
    return __builtin_bit_cast(bf16x8, q);
  };

  auto COMPUTE = [&](int bi){
    const char* base = lb + bi * 24576;
    bf16x8 a0 = LOADFRAG(base, p * 16 + l15);
    bf16x8 a1 = (wid >= 6) ? LOADFRAG(base, (11 - p) * 16 + l15) : a0;
    #pragma unroll
    for (int t = 0; t < 8; t++){
      if (wid >= 6 && t >= 7) break;
      int j = (wid < 6) ? (p + t) : ((t < nFirst) ? (p + 8 + t) : (t + 6));
      bf16x8 bf = (j < 12) ? LOADFRAG(base, j * 16 + l15) : onesf;
      bf16x8 aS = (wid < 6 || t < nFirst) ? a0 : a1;
      acc[t] = __builtin_amdgcn_mfma_f32_16x16x32_bf16(aS, bf, acc[t], 0, 0, 0);
    }
  };

  ISSUE(0, 0);
  for (int c = 0; c < 16; c++){
    __syncthreads();                 // implicit vmcnt(0): our chunk-c loads are landed
    if (c < 15) ISSUE(c + 1, (c + 1) & 1);
    COMPUTE(c & 1);
  }

  // store compact bf16 partials, LANE-MAJOR tiles: element e = lane*4 + r (R7/R10-verified)
  ushort* gp = gpart + (size_t)(b * 128 + slice) * SLICE_ELEMS;
  #pragma unroll
  for (int t = 0; t < 8; t++){
    if (wid >= 6 && t >= 7) break;
    int i = (wid < 6) ? p : ((t < nFirst) ? p : (11 - p));
    int j = (wid < 6) ? (p + t) : ((t < nFirst) ? (p + 8 + t) : (t + 6));
    uint2 u2;
    u2.x = f2bf2(acc[t][0], acc[t][1]);
    u2.y = f2bf2(acc[t][2], acc[t][3]);
    if (j < 12){
      int F = 12 * i - (i * (i - 1)) / 2 + (j - i);
      *(uint2*)(gp + F * 256 + lane * 4) = u2;
    } else if (l15 == 0){
      *(uint2*)(gp + ONES_OFF_E + i * 16 + hi * 4) = u2;
    }
  }
}

// ---------------- K2: reduce compact partials -> G_aug [2][192][193] (mirrored); + WkT
__global__ __launch_bounds__(1024) void k_reduce(const ushort* __restrict__ gpart,
                                                 float* __restrict__ gaug,
                                                 const float* __restrict__ qkv_w,
                                                 float* __restrict__ wkT){
  int blk = blockIdx.x, tid = threadIdx.x;
  if (blk < 180){
    __shared__ float red[4][256];
    int b = blk / 90, slot = blk % 90;
    int q = tid >> 8, e = tid & 255;
    float sum = 0.f;
    if (slot < 78){
      const ushort* pp = gpart + (size_t)(b * 128 + q) * SLICE_ELEMS + slot * 256 + e;
      #pragma unroll 8
      for (int k2 = 0; k2 < 32; k2++) sum += bf2f(pp[(size_t)k2 * (4 * SLICE_ELEMS)]);
    } else if (e < 16){
      int i = slot - 78;
      const ushort* pp = gpart + (size_t)(b * 128 + q) * SLICE_ELEMS + ONES_OFF_E + i * 16 + e;
      #pragma unroll 8
      for (int k2 = 0; k2 < 32; k2++) sum += bf2f(pp[(size_t)k2 * (4 * SLICE_ELEMS)]);
    }
    red[q][e] = sum;
    __syncthreads();
    if (tid < 256){
      float tot = red[0][tid] + red[1][tid] + red[2][tid] + red[3][tid];
      if (slot < 78){
        int i = 0, off = 0;
        while (slot >= off + (12 - i)){ off += 12 - i; i++; }
        int j = i + (slot - off);
        // lane-major remap: e = lane*4 + r -> row = hi*4+r, col = l15
        int e2 = tid;
        int row = ((e2 >> 6) << 2) | (e2 & 3);
        int col = (e2 >> 2) & 15;
        int R = i * 16 + row, Cc = j * 16 + col;
        gaug[((size_t)b * C192 + R) * 193 + Cc] = tot;
        gaug[((size_t)b * C192 + Cc) * 193 + R] = tot;
      } else if (tid < 16){
        int i = slot - 78;
        gaug[((size_t)b * C192 + i * 16 + tid) * 193 + 192] = tot;
      }
    }
  } else {
    int idx = (blk - 180) * 1024 + tid;
    if (idx < 36864){
      int d = idx / 192, e = idx % 192;
      wkT[e * 192 + d] = qkv_w[(192 + d) * 192 + e];
    }
  }
}

// ---------------- T1: P_aug = Wq*G_aug, R_aug = Wk*G_aug; plus q/k norms
__global__ __launch_bounds__(256) void k_pr(const float* __restrict__ gaug,
                                            const float* __restrict__ qkv_w,
                                            const float* __restrict__ qkv_b,
                                            float* __restrict__ pr,
                                            float* __restrict__ norms){
  __shared__ float red[4];
  __shared__ float uSh;
  int blk = blockIdx.x, tid = threadIdx.x;
  int b = blk / 384, which = (blk / 192) % 2, c = blk % 192;
  const float* wrow = qkv_w + (which * 192 + c) * 192;
  float acc = 0.f;
  if (tid < 193){
    const float* g = gaug + (size_t)b * C192 * 193 + tid;
    #pragma unroll 4
    for (int e = 0; e < 192; e++) acc += wrow[e] * g[(size_t)e * 193];
    pr[(((size_t)b * 2 + which) * 192 + c) * 193 + tid] = acc;
  }
  if (tid == 192) uSh = acc;
  float v = (tid < 192) ? acc * wrow[tid] : 0.f;
  for (int o = 32; o > 0; o >>= 1) v += __shfl_down(v, o, 64);
  if ((tid & 63) == 0) red[tid >> 6] = v;
  __syncthreads();
  if (tid == 0){
    float s = red[0] + red[1] + red[2] + red[3];
    float bias = qkv_b[which * 192 + c];
    float n2 = s + 2.f * bias * uSh + 65536.f * bias * bias;
    norms[(b * 2 + which) * 192 + c] = fmaxf(sqrtf(fmaxf(n2, 0.f)), EPS_N);
  }
}

// ---------------- T3+T4 fused: softmax row -> U_aug row   [2][192][193]
__global__ __launch_bounds__(256) void k_attn_u(const float* __restrict__ pr,
                                                const float* __restrict__ wkT,
                                                const float* __restrict__ norms,
                                                const float* __restrict__ qkv_b,
                                                const float* __restrict__ temperature,
                                                const float* __restrict__ qkv_w,
                                                float* __restrict__ uaug){
  __shared__ float Pc[193];
  __shared__ float red[4];
  __shared__ float bcast;
  int blk = blockIdx.x, tid = threadIdx.x;
  int b = blk / 192, c = blk % 192;
  if (tid < 193) Pc[tid] = pr[(((size_t)b * 2 + 0) * 192 + c) * 193 + tid];
  __syncthreads();
  int d = tid;
  float logit = -1e30f, pv = 0.f;
  if (d < 192){
    float sS = 0.f;
    #pragma unroll 4
    for (int e = 0; e < 192; e++) sS += Pc[e] * wkT[e * 192 + d];
    float bq = qkv_b[c], bk = qkv_b[192 + d];
    float w2 = pr[(((size_t)b * 2 + 1) * 192 + d) * 193 + 192];
    float Sv = sS + Pc[192] * bk + bq * w2 + 65536.f * bq * bk;
    float nq = norms[(b * 2 + 0) * 192 + c];
    float nk = norms[(b * 2 + 1) * 192 + d];
    logit = temperature[0] * Sv / (nq * nk);
  }
  float m = logit;
  for (int o = 32; o > 0; o >>= 1) m = fmaxf(m, __shfl_down(m, o, 64));
  if ((tid & 63) == 0) red[tid >> 6] = m;
  __syncthreads();
  if (tid == 0) bcast = fmaxf(fmaxf(red[0], red[1]), fmaxf(red[2], red[3]));
  __syncthreads();
  m = bcast;
  pv = (d < 192) ? __expf(logit - m) : 0.f;
  float s = pv;
  for (int o = 32; o > 0; o >>= 1) s += __shfl_down(s, o, 64);
  __syncthreads();
  if ((tid & 63) == 0) red[tid >> 6] = s;
  __syncthreads();
  if (tid == 0) bcast = red[0] + red[1] + red[2] + red[3];
  __syncthreads();
  float aw = (d < 192) ? (pv / bcast) : 0.f;
  __syncthreads();
  if (d < 192) Pc[d] = aw;        // reuse Pc as softmax row
  __syncthreads();
  int e = tid;
  if (e <= 192){
    float acc = 0.f;
    if (e < 192){
      #pragma unroll 4
      for (int d2 = 0; d2 < 192; d2++) acc += Pc[d2] * qkv_w[(384 + d2) * 192 + e];
    } else {
      #pragma unroll 4
      for (int d2 = 0; d2 < 192; d2++) acc += Pc[d2] * qkv_b[384 + d2];
    }
    uaug[((size_t)b * 192 + c) * 193 + e] = acc;
  }
}

// ---------------- T5: F = proj_w @ U (bf16), g = proj_w@h + proj_b
__global__ __launch_bounds__(256) void k_f(const float* __restrict__ uaug,
                                           const float* __restrict__ proj_w,
                                           const float* __restrict__ proj_b,
                                           ushort* __restrict__ fb,
                                           float* __restrict__ gvec){
  __shared__ float pw[192];
  int blk = blockIdx.x, tid = threadIdx.x;
  int b = blk / 192, f = blk % 192;
  if (tid < 192) pw[tid] = proj_w[f * 192 + tid];
  __syncthreads();
  int e = tid;
  if (e <= 192){
    float acc = 0.f;
    const float* u = uaug + (size_t)b * 192 * 193 + e;
    #pragma unroll 4
    for (int c2 = 0; c2 < 192; c2++) acc += pw[c2] * u[(size_t)c2 * 193];
    if (e < 192) fb[((size_t)b * 192 + f) * 192 + e] = (ushort)f2bf1(acc);
    else gvec[b * 192 + f] = acc + proj_b[f];
  }
}

// ---------------- K3: out = F @ x + g 1^T  (fp32 x reads, 12-deep load batches,
// staging convert via v_cvt_pk_bf16_f32 — R13-verified, 125.8 us total)
// Stage x-chunk TRANSPOSED into LDS [sp:128][chan:192], channel-PAIRED ds_write_b32,
// dual-bit XOR swizzle g(sp) = (sp&7)^((sp>>3)&7) on write AND read (R3-verified).
__global__ __launch_bounds__(256, 3) void k_out(const float* __restrict__ x,
                                                const ushort* __restrict__ fb,
                                                const float* __restrict__ gvec,
                                                float* __restrict__ out){
  __shared__ ushort xt[128 * 192];   // [sp][chan], row = 384 B
  char* lb = (char*)xt;
  const int tid = threadIdx.x;
  const int lane = tid & 63, wid = tid >> 6;
  const int l15 = lane & 15, hi = lane >> 4;
  const int b = blockIdx.x >> 9, cb = blockIdx.x & 511;
  const int j0 = cb * 128;

  const float* xg = x + ((size_t)b * C192) * NSP + j0;
  #pragma unroll
  for (int half = 0; half < 2; half++){
    float4 ra[12];
    #pragma unroll
    for (int ii = 0; ii < 3; ii++){
      int unit = (half * 3 + ii) * 256 + tid;
      int cp = unit >> 4, s8 = unit & 15;
      int c0 = cp * 2, sp0 = s8 * 8;
      const float* r0 = xg + (size_t)c0 * NSP + sp0;
      const float* r1 = xg + (size_t)(c0 + 1) * NSP + sp0;
      ra[4 * ii]     = *(const float4*)(r0);
      ra[4 * ii + 1] = *(const float4*)(r0 + 4);
      ra[4 * ii + 2] = *(const float4*)(r1);
      ra[4 * ii + 3] = *(const float4*)(r1 + 4);
    }
    #pragma unroll
    for (int ii = 0; ii < 3; ii++){
      int unit = (half * 3 + ii) * 256 + tid;
      int cp = unit >> 4, s8 = unit & 15;
      int c0 = cp * 2, sp0 = s8 * 8;
      float fa[8] = {ra[4*ii].x, ra[4*ii].y, ra[4*ii].z, ra[4*ii].w,
                     ra[4*ii+1].x, ra[4*ii+1].y, ra[4*ii+1].z, ra[4*ii+1].w};
      float fc[8] = {ra[4*ii+2].x, ra[4*ii+2].y, ra[4*ii+2].z, ra[4*ii+2].w,
                     ra[4*ii+3].x, ra[4*ii+3].y, ra[4*ii+3].z, ra[4*ii+3].w};
      #pragma unroll
      for (int s = 0; s < 8; s++){
        int sp = sp0 + s;
        int byte = sp * 384 + c0 * 2;
        byte ^= (((sp & 7) ^ ((sp >> 3) & 7)) << 4);
        uint pk;
        asm("v_cvt_pk_bf16_f32 %0, %1, %2" : "=v"(pk) : "v"(fa[s]), "v"(fc[s]));
        *(uint*)(lb + byte) = pk;
      }
    }
  }

  float gfr[3][4];
  #pragma unroll
  for (int i = 0; i < 3; i++)
    #pragma unroll
    for (int r = 0; r < 4; r++)
      gfr[i][r] = gvec[b * 192 + (wid * 3 + i) * 16 + hi * 4 + r];

  f32x4 acc[3][8];
  #pragma unroll
  for (int i = 0; i < 3; i++)
    #pragma unroll
    for (int j = 0; j < 8; j++)
      acc[i][j] = (f32x4){0.f, 0.f, 0.f, 0.f};

  __syncthreads();

  for (int w = 0; w < 6; w++){
    bf16x8 aF[3];
    #pragma unroll
    for (int i = 0; i < 3; i++){
      const ushort* fr = fb + ((size_t)b * 192 + (wid * 3 + i) * 16 + l15) * 192;
      aF[i] = *(const bf16x8*)(fr + w * 32 + hi * 8);
    }
    #pragma unroll
    for (int ct = 0; ct < 8; ct++){
      int sp = ct * 16 + l15;
      int byte = sp * 384 + w * 64 + hi * 16;
      byte ^= (((sp & 7) ^ ((sp >> 3) & 7)) << 4);
      bf16x8 bf = *(const bf16x8*)(lb + byte);
      #pragma unroll
      for (int i = 0; i < 3; i++)
        acc[i][ct] = __builtin_amdgcn_mfma_f32_16x16x32_bf16(aF[i], bf, acc[i][ct], 0, 0, 0);
    }
  }

  #pragma unroll
  for (int i = 0; i < 3; i++){
    int row0 = (wid * 3 + i) * 16 + hi * 4;
    #pragma unroll
    for (int ct = 0; ct < 8; ct++){
      int sp = j0 + ct * 16 + l15;
      float* ob = out + ((size_t)b * C192 + row0) * NSP + sp;
      #pragma unroll
      for (int r = 0; r < 4; r++) ob[(size_t)r * NSP] = acc[i][ct][r] + gfr[i][r];
    }
  }
}

extern "C" void kernel_launch(void* const* d_in, const int* in_sizes, int n_in,
                              void* d_out, int out_size, void* d_ws, size_t ws_size,
                              hipStream_t stream){
  const float* x           = (const float*)d_in[0];
  const float* temperature = (const float*)d_in[1];
  const float* qkv_w       = (const float*)d_in[2];
  const float* qkv_b       = (const float*)d_in[3];
  const float* proj_w      = (const float*)d_in[4];
  const float* proj_b      = (const float*)d_in[5];
  float* out = (float*)d_out;
  char* ws = (char*)d_ws;

  ushort* gpart = (ushort*)(ws);                 // 256*20224*2 = 10,354,688
  float*  gaug  = (float*) (ws + 10354688);      // 296,448
  float*  pr    = (float*) (ws + 10651136);      // 592,896
  float*  wkT   = (float*) (ws + 11244032);      // 147,456
  float*  norms = (float*) (ws + 11391488);      // 3,072
  float*  uaug  = (float*) (ws + 11394560);      // 296,448
  ushort* fb    = (ushort*)(ws + 11691008);      // 147,456
  float*  gvec  = (float*) (ws + 11838464);      // 1,536

  hipLaunchKernelGGL(k_gram,   dim3(256),  dim3(768),  0, stream, x, gpart);
  hipLaunchKernelGGL(k_reduce, dim3(216),  dim3(1024), 0, stream, gpart, gaug, qkv_w, wkT);
  hipLaunchKernelGGL(k_pr,     dim3(768),  dim3(256),  0, stream, gaug, qkv_w, qkv_b, pr, norms);
  hipLaunchKernelGGL(k_attn_u, dim3(384),  dim3(256),  0, stream, pr, wkT, norms, qkv_b, temperature, qkv_w, uaug);
  hipLaunchKernelGGL(k_f,      dim3(384),  dim3(256),  0, stream, uaug, proj_w, proj_b, fb, gvec);
  hipLaunchKernelGGL(k_out,    dim3(1024), dim3(256),  0, stream, x, fb, gvec, out);
}